// Round 6
// baseline (162.372 us; speedup 1.0000x reference)
//
#include <hip/hip_runtime.h>
#include <hip/hip_bf16.h>
#include <math.h>

#define DEMB 64
#define BM   64
#define KSMAX 32   // 66*32=2112 blocks ~= 8 blocks/CU
#define APAD 40    // LDS row stride in ushorts (80 B): bank-conflict-free b128

using short8 = __attribute__((ext_vector_type(8))) short;
using u16x8  = __attribute__((ext_vector_type(8))) unsigned short;
using f32x4  = __attribute__((ext_vector_type(4))) float;

__device__ __forceinline__ unsigned short f2bf(float x) {
    union { float f; unsigned u; } v; v.f = x;
    unsigned r = v.u + 0x7fffu + ((v.u >> 16) & 1u);   // RNE
    return (unsigned short)(r >> 16);
}

// W [Din][64] fp32 -> Wt [64][Wstride] bf16 (transposed, K zero-padded)
__global__ __launch_bounds__(256) void prep_wt(
    const float* __restrict__ W, unsigned short* __restrict__ Wt,
    int Din, int Wstride)
{
    __shared__ unsigned short tile[64][65];
    const int k0 = blockIdx.x * 64;
    const int tid = threadIdx.x;
    #pragma unroll
    for (int i = 0; i < 16; ++i) {
        int kk = i * 4 + (tid >> 6);
        int c  = tid & 63;
        int k  = k0 + kk;
        float x = (k < Din) ? W[(size_t)k * DEMB + c] : 0.f;
        tile[kk][c] = f2bf(x);
    }
    __syncthreads();
    #pragma unroll
    for (int i = 0; i < 16; ++i) {
        int c  = i * 4 + (tid >> 6);
        int kk = tid & 63;
        Wt[(size_t)c * Wstride + k0 + kk] = tile[kk][c];
    }
}

// MFMA GEMM. A: reg-staged -> padded LDS (bf16), conflict-free.
// B: per-lane fragments loaded DIRECTLY from L2-resident Wt (no LDS) —
// B frags are wave-independent, LDS staging was 4x read amplification.
__global__ __launch_bounds__(256) void gemm_mfma(
    const float* __restrict__ Xq, const float* __restrict__ Xs,
    const unsigned short* __restrict__ Wt,
    float* __restrict__ qpart, float* __restrict__ spart,
    int Q, int S, int Din, int Wstride, int nQb, int cpk, int nchunk)
{
    __shared__ unsigned short As[2][BM * APAD];

    const int tid  = threadIdx.x;
    const int wave = tid >> 6;
    const int lane = tid & 63;
    const int kg   = blockIdx.y;

    const bool isS = (int)blockIdx.x >= nQb;
    const float* X = isS ? Xs : Xq;
    const int nrows = isS ? S : Q;
    const int r0 = (isS ? ((int)blockIdx.x - nQb) : (int)blockIdx.x) * BM;
    float* part = isS ? spart : qpart;
    const int prow = isS ? 128 : Q;

    // A staging map: thread -> (row = tid>>2, k-offset = (tid&3)*8)
    const int arow = tid >> 2;
    const int ak   = (tid & 3) * 8;
    const bool aval = (r0 + arow) < nrows;
    const float* aptr = X + (size_t)(r0 + arow) * Din;

    // fragment coords
    const int col16 = lane & 15;
    const int frow  = 16 * wave + col16;
    const int fk    = (lane >> 4) * 8;
    const unsigned short* bptr = Wt + (size_t)col16 * Wstride + fk;

    f32x4 acc[4] = { {0.f,0.f,0.f,0.f}, {0.f,0.f,0.f,0.f},
                     {0.f,0.f,0.f,0.f}, {0.f,0.f,0.f,0.f} };

    const int c0 = kg * cpk;
    int c1 = c0 + cpk; if (c1 > nchunk) c1 = nchunk;

#define LOADA(c, A0, A1) do {                                                  \
    const int k0_ = (c) * 32;                                                  \
    const int kk_ = k0_ + ak;                                                  \
    if (aval && kk_ + 8 <= Din) {                                              \
        A0 = *reinterpret_cast<const float4*>(aptr + kk_);                     \
        A1 = *reinterpret_cast<const float4*>(aptr + kk_ + 4);                 \
    } else {                                                                   \
        A0 = make_float4(0.f,0.f,0.f,0.f); A1 = make_float4(0.f,0.f,0.f,0.f);  \
    }                                                                          \
} while (0)

#define LOADB(c, BV) do {                                                      \
    const int k0_ = (c) * 32;                                                  \
    BV[0] = *reinterpret_cast<const u16x8*>(bptr + k0_);                       \
    BV[1] = *reinterpret_cast<const u16x8*>(bptr + (size_t)16 * Wstride + k0_);\
    BV[2] = *reinterpret_cast<const u16x8*>(bptr + (size_t)32 * Wstride + k0_);\
    BV[3] = *reinterpret_cast<const u16x8*>(bptr + (size_t)48 * Wstride + k0_);\
} while (0)

#define WRITEA(P, A0, A1) do {                                                 \
    u16x8 ap_ = { f2bf(A0.x), f2bf(A0.y), f2bf(A0.z), f2bf(A0.w),              \
                  f2bf(A1.x), f2bf(A1.y), f2bf(A1.z), f2bf(A1.w) };            \
    *reinterpret_cast<u16x8*>(&As[P][arow * APAD + ak]) = ap_;                 \
} while (0)

#define COMPUTE(P, BV) do {                                                    \
    short8 af_ = *reinterpret_cast<const short8*>(&As[P][frow * APAD + fk]);   \
    acc[0] = __builtin_amdgcn_mfma_f32_16x16x32_bf16(af_, (short8)BV[0], acc[0], 0, 0, 0); \
    acc[1] = __builtin_amdgcn_mfma_f32_16x16x32_bf16(af_, (short8)BV[1], acc[1], 0, 0, 0); \
    acc[2] = __builtin_amdgcn_mfma_f32_16x16x32_bf16(af_, (short8)BV[2], acc[2], 0, 0, 0); \
    acc[3] = __builtin_amdgcn_mfma_f32_16x16x32_bf16(af_, (short8)BV[3], acc[3], 0, 0, 0); \
} while (0)

    float4 a0, a1;
    u16x8 bA[4], bB[4];

    // prologue: chunk c0 -> LDS buf0 + B regs
    LOADA(c0, a0, a1);
    LOADB(c0, bA);
    WRITEA(0, a0, a1);
    __syncthreads();

    int c = c0, cur = 0;
    while (c < c1) {
        // even step: compute chunk c from As[cur] + bA
        {
            const int cn = c + 1;
            const bool pf = cn < c1;
            if (pf) { LOADA(cn, a0, a1); LOADB(cn, bB); }
            COMPUTE(cur, bA);
            if (pf) WRITEA(cur ^ 1, a0, a1);
            __syncthreads();
            cur ^= 1; ++c;
        }
        if (c >= c1) break;
        // odd step: compute chunk c from As[cur] + bB
        {
            const int cn = c + 1;
            const bool pf = cn < c1;
            if (pf) { LOADA(cn, a0, a1); LOADB(cn, bA); }
            COMPUTE(cur, bB);
            if (pf) WRITEA(cur ^ 1, a0, a1);
            __syncthreads();
            cur ^= 1; ++c;
        }
    }

#undef LOADA
#undef LOADB
#undef WRITEA
#undef COMPUTE

    // epilogue: C layout col=lane&15, row=(lane>>4)*4+i
    #pragma unroll
    for (int cb = 0; cb < 4; ++cb) {
        #pragma unroll
        for (int i = 0; i < 4; ++i) {
            int row = r0 + 16 * wave + (lane >> 4) * 4 + i;
            if (row < nrows)
                part[((size_t)kg * prow + row) * DEMB + 16 * cb + col16] = acc[cb][i];
        }
    }
}

// Reduce support partials + bias, L2-normalize -> sn [S][64]
__global__ void support_finalize(const float* __restrict__ spart,
                                 const float* __restrict__ bias,
                                 float* __restrict__ sn, int S, int nkg)
{
    int s = blockIdx.x;
    int c = threadIdx.x;  // 64
    float e = bias[c];
    for (int g = 0; g < nkg; ++g)
        e += spart[((size_t)g * 128 + s) * DEMB + c];
    float ss = e * e;
    #pragma unroll
    for (int o = 32; o >= 1; o >>= 1) ss += __shfl_xor(ss, o, 64);
    sn[(size_t)s * DEMB + c] = e / fmaxf(sqrtf(ss), 1e-8f);
}

// Fused: query reduce+bias+normalize, cosine sims, softmax, one-hot bins.
__global__ __launch_bounds__(256) void attend(
    const float* __restrict__ qpart, const float* __restrict__ sn_g,
    const float* __restrict__ bias, const int* __restrict__ labels,
    const int* __restrict__ p_nway, float* __restrict__ out,
    int S, int Q, int nkg)
{
    __shared__ float sn[100][65];
    __shared__ float qn[4][64];
    __shared__ float bins[4][32];
    __shared__ int   lab[100];

    const int tid  = threadIdx.x;
    const int w    = tid >> 6;
    const int lane = tid & 63;
    const int nw   = *p_nway;

    for (int i = tid; i < S * DEMB; i += 256) sn[i >> 6][i & 63] = sn_g[i];
    if (tid < S) lab[tid] = labels[tid];

    const int q = blockIdx.x * 4 + w;

    float e = bias[lane];
    for (int g = 0; g < nkg; ++g)
        e += qpart[((size_t)g * Q + q) * DEMB + lane];
    float ss = e * e;
    #pragma unroll
    for (int o = 32; o >= 1; o >>= 1) ss += __shfl_xor(ss, o, 64);
    e /= fmaxf(sqrtf(ss), 1e-8f);
    qn[w][lane] = e;
    if (lane < 32) bins[w][lane] = 0.f;
    __syncthreads();

    const bool v1 = (lane + 64) < S;
    const int  s1 = v1 ? lane + 64 : 0;
    float sim0 = 0.f, sim1 = 0.f;
    #pragma unroll 8
    for (int c = 0; c < DEMB; ++c) {
        float qc = qn[w][c];
        sim0 += qc * sn[lane][c];
        sim1 += qc * sn[s1][c];
    }
    if (!v1) sim1 = -INFINITY;

    float lm = fmaxf(sim0, sim1);
    #pragma unroll
    for (int o = 32; o >= 1; o >>= 1) lm = fmaxf(lm, __shfl_xor(lm, o, 64));
    float e0 = __expf(sim0 - lm);
    float e1 = v1 ? __expf(sim1 - lm) : 0.f;
    float d = e0 + e1;
    #pragma unroll
    for (int o = 32; o >= 1; o >>= 1) d += __shfl_xor(d, o, 64);

    atomicAdd(&bins[w][lab[lane]], e0);
    if (v1) atomicAdd(&bins[w][lab[s1]], e1);
    __syncthreads();

    if (lane < nw) out[(size_t)q * nw + lane] = bins[w][lane] / d;
}

extern "C" void kernel_launch(void* const* d_in, const int* in_sizes, int n_in,
                              void* d_out, int out_size, void* d_ws, size_t ws_size,
                              hipStream_t stream)
{
    const float* sup    = (const float*)d_in[0];
    const int*   labels = (const int*)d_in[1];
    const float* qry    = (const float*)d_in[2];
    const int*   p_nway = (const int*)d_in[3];
    const float* W      = (const float*)d_in[5];
    const float* bias   = (const float*)d_in[6];
    float* out = (float*)d_out;

    const int D   = DEMB;                 // 64
    const int Din = in_sizes[5] / D;      // 21168
    const int Q   = in_sizes[2] / Din;    // 4096
    const int S   = in_sizes[1];          // 100

    const int nchunk  = (Din + 31) / 32;  // 662
    const int Wstride = nchunk * 32;      // 21184

    // workspace layout
    char* wsb = (char*)d_ws;
    size_t wt_bytes = (size_t)64 * Wstride * sizeof(unsigned short); // 2.71 MB
    wt_bytes = (wt_bytes + 255) & ~(size_t)255;
    size_t sn_bytes = (size_t)S * D * sizeof(float);
    sn_bytes = (sn_bytes + 255) & ~(size_t)255;
    size_t per_ks = ((size_t)Q * D + 128 * D) * sizeof(float);

    size_t fixed = wt_bytes + sn_bytes;
    int ks = 1;
    if (ws_size > fixed + per_ks) {
        size_t avail = (ws_size - fixed) / per_ks;
        ks = (int)(avail < KSMAX ? avail : KSMAX);
        if (ks < 1) ks = 1;
    }
    const int cpk = (nchunk + ks - 1) / ks;       // chunks per K-group
    const int nkg = (nchunk + cpk - 1) / cpk;     // actual # groups

    unsigned short* Wt = (unsigned short*)wsb;
    float* sn    = (float*)(wsb + wt_bytes);
    float* spart = (float*)(wsb + wt_bytes + sn_bytes);
    float* qpart = spart + (size_t)nkg * 128 * D;

    hipLaunchKernelGGL(prep_wt, dim3((Din + 63) / 64), dim3(256), 0, stream,
                       W, Wt, Din, Wstride);

    const int nQb = (Q + BM - 1) / BM;          // 64
    const int nSb = (S + BM - 1) / BM;          // 2
    hipLaunchKernelGGL(gemm_mfma, dim3(nQb + nSb, nkg), dim3(256), 0, stream,
                       qry, sup, Wt, qpart, spart, Q, S, Din, Wstride, nQb, cpk, nchunk);

    hipLaunchKernelGGL(support_finalize, dim3(S), dim3(64), 0, stream,
                       spart, bias, sn, S, nkg);

    hipLaunchKernelGGL(attend, dim3(Q / 4), dim3(256), 0, stream,
                       qpart, sn, bias, labels, p_nway, out, S, Q, nkg);
}

// Round 7
// 143.440 us; speedup vs baseline: 1.1320x; 1.1320x over previous
//
#include <hip/hip_runtime.h>
#include <hip/hip_bf16.h>
#include <math.h>

#define DEMB 64
#define BM   64
#define KSMAX 32   // 66*32=2112 blocks

using short8 = __attribute__((ext_vector_type(8))) short;
using u16x8  = __attribute__((ext_vector_type(8))) unsigned short;
using f32x4  = __attribute__((ext_vector_type(4))) float;

__device__ __forceinline__ unsigned short f2bf(float x) {
    union { float f; unsigned u; } v; v.f = x;
    unsigned r = v.u + 0x7fffu + ((v.u >> 16) & 1u);   // RNE
    return (unsigned short)(r >> 16);
}

// W [Din][64] fp32 -> Wt [64][Wstride] bf16 (transposed, K zero-padded)
__global__ __launch_bounds__(256) void prep_wt(
    const float* __restrict__ W, unsigned short* __restrict__ Wt,
    int Din, int Wstride)
{
    __shared__ unsigned short tile[64][65];
    const int k0 = blockIdx.x * 64;
    const int tid = threadIdx.x;
    #pragma unroll
    for (int i = 0; i < 16; ++i) {
        int kk = i * 4 + (tid >> 6);
        int c  = tid & 63;
        int k  = k0 + kk;
        float x = (k < Din) ? W[(size_t)k * DEMB + c] : 0.f;
        tile[kk][c] = f2bf(x);
    }
    __syncthreads();
    #pragma unroll
    for (int i = 0; i < 16; ++i) {
        int c  = i * 4 + (tid >> 6);
        int kk = tid & 63;
        Wt[(size_t)c * Wstride + k0 + kk] = tile[kk][c];
    }
}

// MFMA GEMM: round-5 structure (A+B LDS-staged, plain __syncthreads dbuf),
// with A global loads BATCHED 4 chunks ahead into registers so each
// 4-thread row-quartet requests 512 B contiguous per row per batch
// (DRAM page clustering), instead of 128 B per chunk.
__global__ __launch_bounds__(256) void gemm_mfma(
    const float* __restrict__ Xq, const float* __restrict__ Xs,
    const unsigned short* __restrict__ Wt,
    float* __restrict__ qpart, float* __restrict__ spart,
    int Q, int S, int Din, int Wstride, int nQb, int cpk, int nchunk)
{
    __shared__ unsigned short As[2][BM * 32];
    __shared__ unsigned short Ws[2][64 * 32];

    const int tid  = threadIdx.x;
    const int wave = tid >> 6;
    const int lane = tid & 63;
    const int kg   = blockIdx.y;

    const bool isS = (int)blockIdx.x >= nQb;
    const float* X = isS ? Xs : Xq;
    const int nrows = isS ? S : Q;
    const int r0 = (isS ? ((int)blockIdx.x - nQb) : (int)blockIdx.x) * BM;
    float* part = isS ? spart : qpart;
    const int prow = isS ? 128 : Q;

    // staging maps: thread -> (row = tid>>2, k-offset = (tid&3)*8)
    const int arow = tid >> 2;
    const int ak   = (tid & 3) * 8;
    const bool aval = (r0 + arow) < nrows;
    const float* aptr = X + (size_t)(r0 + arow) * Din;
    const unsigned short* wptr = Wt + (size_t)(tid >> 2) * Wstride + (tid & 3) * 8;

    // fragment coords
    const int col16 = lane & 15;
    const int frow  = 16 * wave + col16;
    const int fk    = (lane >> 4) * 8;

    f32x4 acc[4] = { {0.f,0.f,0.f,0.f}, {0.f,0.f,0.f,0.f},
                     {0.f,0.f,0.f,0.f}, {0.f,0.f,0.f,0.f} };

    const int c0 = kg * cpk;
    int c1 = c0 + cpk; if (c1 > nchunk) c1 = nchunk;

#define LOADA(c, A0, A1) do {                                                  \
    const int kk_ = (c) * 32 + ak;                                             \
    if (aval && kk_ + 8 <= Din) {                                              \
        A0 = *reinterpret_cast<const float4*>(aptr + kk_);                     \
        A1 = *reinterpret_cast<const float4*>(aptr + kk_ + 4);                 \
    } else {                                                                   \
        A0 = make_float4(0.f,0.f,0.f,0.f); A1 = make_float4(0.f,0.f,0.f,0.f);  \
    }                                                                          \
} while (0)

#define LOADB(c, BV) do {                                                      \
    BV = *reinterpret_cast<const u16x8*>(wptr + (size_t)(c) * 32);             \
} while (0)

#define WRITEAB(P, A0, A1, BV) do {                                            \
    u16x8 ap_ = { f2bf(A0.x), f2bf(A0.y), f2bf(A0.z), f2bf(A0.w),              \
                  f2bf(A1.x), f2bf(A1.y), f2bf(A1.z), f2bf(A1.w) };            \
    *reinterpret_cast<u16x8*>(&As[P][arow * 32 + ak]) = ap_;                   \
    *reinterpret_cast<u16x8*>(&Ws[P][tid * 8]) = BV;                           \
} while (0)

#define COMPUTE(P) do {                                                        \
    short8 af_ = *reinterpret_cast<const short8*>(&As[P][frow * 32 + fk]);     \
    short8 b0_ = *reinterpret_cast<const short8*>(&Ws[P][( 0 + col16) * 32 + fk]); \
    short8 b1_ = *reinterpret_cast<const short8*>(&Ws[P][(16 + col16) * 32 + fk]); \
    short8 b2_ = *reinterpret_cast<const short8*>(&Ws[P][(32 + col16) * 32 + fk]); \
    short8 b3_ = *reinterpret_cast<const short8*>(&Ws[P][(48 + col16) * 32 + fk]); \
    acc[0] = __builtin_amdgcn_mfma_f32_16x16x32_bf16(af_, b0_, acc[0], 0, 0, 0); \
    acc[1] = __builtin_amdgcn_mfma_f32_16x16x32_bf16(af_, b1_, acc[1], 0, 0, 0); \
    acc[2] = __builtin_amdgcn_mfma_f32_16x16x32_bf16(af_, b2_, acc[2], 0, 0, 0); \
    acc[3] = __builtin_amdgcn_mfma_f32_16x16x32_bf16(af_, b3_, acc[3], 0, 0, 0); \
} while (0)

    float4 p0a,p0b,p1a,p1b,p2a,p2b,p3a,p3b;   // current A batch (chunks b..b+3)
    float4 q0a,q0b,q1a,q1b,q2a,q2b,q3a,q3b;   // next A batch (chunks b+4..b+7)
    p1a=p1b=p2a=p2b=p3a=p3b=make_float4(0.f,0.f,0.f,0.f);
    q0a=q0b=q1a=q1b=q2a=q2b=q3a=q3b=make_float4(0.f,0.f,0.f,0.f);

    // prologue: batch-load chunks c0..c0+3 (one 512 B/row burst), stage c0
    LOADA(c0, p0a, p0b);
    if (c0+1 < c1) LOADA(c0+1, p1a, p1b);
    if (c0+2 < c1) LOADA(c0+2, p2a, p2b);
    if (c0+3 < c1) LOADA(c0+3, p3a, p3b);
    {
        u16x8 wv; LOADB(c0, wv);
        WRITEAB(0, p0a, p0b, wv);
    }
    __syncthreads();

    int cur = 0;
    for (int b = c0; b < c1; b += 4) {
        // step 0: compute chunk b; stage b+1
        {
            const bool pf = (b+1 < c1);
            u16x8 w_ = {0,0,0,0,0,0,0,0};
            if (pf) LOADB(b+1, w_);
            COMPUTE(cur);
            if (pf) WRITEAB(cur^1, p1a, p1b, w_);
            __syncthreads();
            cur ^= 1;
        }
        if (b+1 >= c1) break;
        // step 1: compute b+1; stage b+2; ISSUE next A batch (b+4..b+7)
        {
            if (b+4 < c1) LOADA(b+4, q0a, q0b);
            if (b+5 < c1) LOADA(b+5, q1a, q1b);
            if (b+6 < c1) LOADA(b+6, q2a, q2b);
            if (b+7 < c1) LOADA(b+7, q3a, q3b);
            const bool pf = (b+2 < c1);
            u16x8 w_ = {0,0,0,0,0,0,0,0};
            if (pf) LOADB(b+2, w_);
            COMPUTE(cur);
            if (pf) WRITEAB(cur^1, p2a, p2b, w_);
            __syncthreads();
            cur ^= 1;
        }
        if (b+2 >= c1) break;
        // step 2: compute b+2; stage b+3
        {
            const bool pf = (b+3 < c1);
            u16x8 w_ = {0,0,0,0,0,0,0,0};
            if (pf) LOADB(b+3, w_);
            COMPUTE(cur);
            if (pf) WRITEAB(cur^1, p3a, p3b, w_);
            __syncthreads();
            cur ^= 1;
        }
        if (b+3 >= c1) break;
        // step 3: compute b+3; stage b+4 (first chunk of next batch)
        {
            const bool pf = (b+4 < c1);
            u16x8 w_ = {0,0,0,0,0,0,0,0};
            if (pf) LOADB(b+4, w_);
            COMPUTE(cur);
            if (pf) WRITEAB(cur^1, q0a, q0b, w_);
            __syncthreads();
            cur ^= 1;
        }
        // rotate next batch -> current
        p1a=q1a; p1b=q1b; p2a=q2a; p2b=q2b; p3a=q3a; p3b=q3b;
    }

#undef LOADA
#undef LOADB
#undef WRITEAB
#undef COMPUTE

    // epilogue: C layout col=lane&15, row=(lane>>4)*4+i
    #pragma unroll
    for (int cb = 0; cb < 4; ++cb) {
        #pragma unroll
        for (int i = 0; i < 4; ++i) {
            int row = r0 + 16 * wave + (lane >> 4) * 4 + i;
            if (row < nrows)
                part[((size_t)kg * prow + row) * DEMB + 16 * cb + col16] = acc[cb][i];
        }
    }
}

// Reduce support partials + bias, L2-normalize -> sn [S][64]
__global__ void support_finalize(const float* __restrict__ spart,
                                 const float* __restrict__ bias,
                                 float* __restrict__ sn, int S, int nkg)
{
    int s = blockIdx.x;
    int c = threadIdx.x;  // 64
    float e = bias[c];
    for (int g = 0; g < nkg; ++g)
        e += spart[((size_t)g * 128 + s) * DEMB + c];
    float ss = e * e;
    #pragma unroll
    for (int o = 32; o >= 1; o >>= 1) ss += __shfl_xor(ss, o, 64);
    sn[(size_t)s * DEMB + c] = e / fmaxf(sqrtf(ss), 1e-8f);
}

// Fused: query reduce+bias+normalize, cosine sims, softmax, one-hot bins.
__global__ __launch_bounds__(256) void attend(
    const float* __restrict__ qpart, const float* __restrict__ sn_g,
    const float* __restrict__ bias, const int* __restrict__ labels,
    const int* __restrict__ p_nway, float* __restrict__ out,
    int S, int Q, int nkg)
{
    __shared__ float sn[100][65];
    __shared__ float qn[4][64];
    __shared__ float bins[4][32];
    __shared__ int   lab[100];

    const int tid  = threadIdx.x;
    const int w    = tid >> 6;
    const int lane = tid & 63;
    const int nw   = *p_nway;

    for (int i = tid; i < S * DEMB; i += 256) sn[i >> 6][i & 63] = sn_g[i];
    if (tid < S) lab[tid] = labels[tid];

    const int q = blockIdx.x * 4 + w;

    float e = bias[lane];
    for (int g = 0; g < nkg; ++g)
        e += qpart[((size_t)g * Q + q) * DEMB + lane];
    float ss = e * e;
    #pragma unroll
    for (int o = 32; o >= 1; o >>= 1) ss += __shfl_xor(ss, o, 64);
    e /= fmaxf(sqrtf(ss), 1e-8f);
    qn[w][lane] = e;
    if (lane < 32) bins[w][lane] = 0.f;
    __syncthreads();

    const bool v1 = (lane + 64) < S;
    const int  s1 = v1 ? lane + 64 : 0;
    float sim0 = 0.f, sim1 = 0.f;
    #pragma unroll 8
    for (int c = 0; c < DEMB; ++c) {
        float qc = qn[w][c];
        sim0 += qc * sn[lane][c];
        sim1 += qc * sn[s1][c];
    }
    if (!v1) sim1 = -INFINITY;

    float lm = fmaxf(sim0, sim1);
    #pragma unroll
    for (int o = 32; o >= 1; o >>= 1) lm = fmaxf(lm, __shfl_xor(lm, o, 64));
    float e0 = __expf(sim0 - lm);
    float e1 = v1 ? __expf(sim1 - lm) : 0.f;
    float d = e0 + e1;
    #pragma unroll
    for (int o = 32; o >= 1; o >>= 1) d += __shfl_xor(d, o, 64);

    atomicAdd(&bins[w][lab[lane]], e0);
    if (v1) atomicAdd(&bins[w][lab[s1]], e1);
    __syncthreads();

    if (lane < nw) out[(size_t)q * nw + lane] = bins[w][lane] / d;
}

extern "C" void kernel_launch(void* const* d_in, const int* in_sizes, int n_in,
                              void* d_out, int out_size, void* d_ws, size_t ws_size,
                              hipStream_t stream)
{
    const float* sup    = (const float*)d_in[0];
    const int*   labels = (const int*)d_in[1];
    const float* qry    = (const float*)d_in[2];
    const int*   p_nway = (const int*)d_in[3];
    const float* W      = (const float*)d_in[5];
    const float* bias   = (const float*)d_in[6];
    float* out = (float*)d_out;

    const int D   = DEMB;                 // 64
    const int Din = in_sizes[5] / D;      // 21168
    const int Q   = in_sizes[2] / Din;    // 4096
    const int S   = in_sizes[1];          // 100

    const int nchunk  = (Din + 31) / 32;  // 662
    const int Wstride = nchunk * 32;      // 21184

    // workspace layout
    char* wsb = (char*)d_ws;
    size_t wt_bytes = (size_t)64 * Wstride * sizeof(unsigned short); // 2.71 MB
    wt_bytes = (wt_bytes + 255) & ~(size_t)255;
    size_t sn_bytes = (size_t)S * D * sizeof(float);
    sn_bytes = (sn_bytes + 255) & ~(size_t)255;
    size_t per_ks = ((size_t)Q * D + 128 * D) * sizeof(float);

    size_t fixed = wt_bytes + sn_bytes;
    int ks = 1;
    if (ws_size > fixed + per_ks) {
        size_t avail = (ws_size - fixed) / per_ks;
        ks = (int)(avail < KSMAX ? avail : KSMAX);
        if (ks < 1) ks = 1;
    }
    const int cpk = (nchunk + ks - 1) / ks;       // chunks per K-group
    const int nkg = (nchunk + cpk - 1) / cpk;     // actual # groups

    unsigned short* Wt = (unsigned short*)wsb;
    float* sn    = (float*)(wsb + wt_bytes);
    float* spart = (float*)(wsb + wt_bytes + sn_bytes);
    float* qpart = spart + (size_t)nkg * 128 * D;

    hipLaunchKernelGGL(prep_wt, dim3((Din + 63) / 64), dim3(256), 0, stream,
                       W, Wt, Din, Wstride);

    const int nQb = (Q + BM - 1) / BM;          // 64
    const int nSb = (S + BM - 1) / BM;          // 2
    hipLaunchKernelGGL(gemm_mfma, dim3(nQb + nSb, nkg), dim3(256), 0, stream,
                       qry, sup, Wt, qpart, spart, Q, S, Din, Wstride, nQb, cpk, nchunk);

    hipLaunchKernelGGL(support_finalize, dim3(S), dim3(64), 0, stream,
                       spart, bias, sn, S, nkg);

    hipLaunchKernelGGL(attend, dim3(Q / 4), dim3(256), 0, stream,
                       qpart, sn, bias, labels, p_nway, out, S, Q, nkg);
}

// Round 8
// 134.455 us; speedup vs baseline: 1.2076x; 1.0668x over previous
//
#include <hip/hip_runtime.h>
#include <hip/hip_bf16.h>
#include <math.h>

#define DEMB 64
#define BM   64
#define KSMAX 32   // 66*32=2112 blocks ~= 8 blocks/CU
#define APAD 40    // LDS row stride in ushorts (80 B): 2-way banks = free (m136)

using short8 = __attribute__((ext_vector_type(8))) short;
using u16x8  = __attribute__((ext_vector_type(8))) unsigned short;
using f32x4  = __attribute__((ext_vector_type(4))) float;

// native cvt: compiler emits v_cvt_pk_bf16_f32 (RNE), ~4 instrs per 8 elems
__device__ __forceinline__ u16x8 cvt_bf8(float4 a0, float4 a1) {
    union { u16x8 s; __hip_bfloat16 h[8]; } u;
    u.h[0] = __float2bfloat16(a0.x);
    u.h[1] = __float2bfloat16(a0.y);
    u.h[2] = __float2bfloat16(a0.z);
    u.h[3] = __float2bfloat16(a0.w);
    u.h[4] = __float2bfloat16(a1.x);
    u.h[5] = __float2bfloat16(a1.y);
    u.h[6] = __float2bfloat16(a1.z);
    u.h[7] = __float2bfloat16(a1.w);
    return u.s;
}

// W [Din][64] fp32 -> Wt [64][Wstride] bf16 (transposed, K zero-padded)
__global__ __launch_bounds__(256) void prep_wt(
    const float* __restrict__ W, unsigned short* __restrict__ Wt,
    int Din, int Wstride)
{
    __shared__ unsigned short tile[64][65];
    const int k0 = blockIdx.x * 64;
    const int tid = threadIdx.x;
    #pragma unroll
    for (int i = 0; i < 16; ++i) {
        int kk = i * 4 + (tid >> 6);
        int c  = tid & 63;
        int k  = k0 + kk;
        float x = (k < Din) ? W[(size_t)k * DEMB + c] : 0.f;
        union { unsigned short u; __hip_bfloat16 h; } cv;
        cv.h = __float2bfloat16(x);
        tile[kk][c] = cv.u;
    }
    __syncthreads();
    #pragma unroll
    for (int i = 0; i < 16; ++i) {
        int c  = i * 4 + (tid >> 6);
        int kk = tid & 63;
        Wt[(size_t)c * Wstride + k0 + kk] = tile[kk][c];
    }
}

// MFMA GEMM: round-5 structure (A+B LDS-staged, depth-1 reg prefetch,
// plain __syncthreads dbuf), with (a) native cvt_pk bf16 conversion
// (VALU 80%->~30%) and (b) APAD=40 padded LDS (8-way conflicts -> free).
__global__ __launch_bounds__(256) void gemm_mfma(
    const float* __restrict__ Xq, const float* __restrict__ Xs,
    const unsigned short* __restrict__ Wt,
    float* __restrict__ qpart, float* __restrict__ spart,
    int Q, int S, int Din, int Wstride, int nQb, int cpk, int nchunk)
{
    __shared__ unsigned short As[2][BM * APAD];
    __shared__ unsigned short Ws[2][64 * APAD];

    const int tid  = threadIdx.x;
    const int wave = tid >> 6;
    const int lane = tid & 63;
    const int kg   = blockIdx.y;

    const bool isS = (int)blockIdx.x >= nQb;
    const float* X = isS ? Xs : Xq;
    const int nrows = isS ? S : Q;
    const int r0 = (isS ? ((int)blockIdx.x - nQb) : (int)blockIdx.x) * BM;
    float* part = isS ? spart : qpart;
    const int prow = isS ? 128 : Q;

    // staging maps: thread -> (row = tid>>2, k-offset = (tid&3)*8)
    const int srow = tid >> 2;
    const int sk   = (tid & 3) * 8;
    const bool aval = (r0 + srow) < nrows;
    const float* aptr = X + (size_t)(r0 + srow) * Din;
    const unsigned short* wptr = Wt + (size_t)srow * Wstride + sk;

    // fragment coords
    const int col16 = lane & 15;
    const int frow  = 16 * wave + col16;
    const int fk    = (lane >> 4) * 8;

    f32x4 acc[4] = { {0.f,0.f,0.f,0.f}, {0.f,0.f,0.f,0.f},
                     {0.f,0.f,0.f,0.f}, {0.f,0.f,0.f,0.f} };

    const int c0 = kg * cpk;
    int c1 = c0 + cpk; if (c1 > nchunk) c1 = nchunk;

    // prologue: stage chunk c0 into buffer 0
    {
        const int k0 = c0 * 32;
        const int kk = k0 + sk;
        float4 a0 = {}, a1 = {};
        if (aval && kk + 8 <= Din) {
            a0 = *reinterpret_cast<const float4*>(aptr + kk);
            a1 = *reinterpret_cast<const float4*>(aptr + kk + 4);
        }
        u16x8 wv = *reinterpret_cast<const u16x8*>(wptr + k0);
        *reinterpret_cast<u16x8*>(&As[0][srow * APAD + sk]) = cvt_bf8(a0, a1);
        *reinterpret_cast<u16x8*>(&Ws[0][srow * APAD + sk]) = wv;
        __syncthreads();
    }

    int cur = 0;
    for (int c = c0; c < c1; ++c) {
        const int cn = c + 1;
        const bool pf = (cn < c1);
        float4 a0 = {}, a1 = {};
        u16x8 wv = {0,0,0,0,0,0,0,0};
        if (pf) {
            const int k0 = cn * 32;
            const int kk = k0 + sk;
            if (aval && kk + 8 <= Din) {
                a0 = *reinterpret_cast<const float4*>(aptr + kk);
                a1 = *reinterpret_cast<const float4*>(aptr + kk + 4);
            }
            wv = *reinterpret_cast<const u16x8*>(wptr + k0);
        }

        short8 af = *reinterpret_cast<const short8*>(&As[cur][frow * APAD + fk]);
        #pragma unroll
        for (int cb = 0; cb < 4; ++cb) {
            short8 bf = *reinterpret_cast<const short8*>(
                &Ws[cur][(16 * cb + col16) * APAD + fk]);
            acc[cb] = __builtin_amdgcn_mfma_f32_16x16x32_bf16(af, bf, acc[cb], 0, 0, 0);
        }

        if (pf) {
            *reinterpret_cast<u16x8*>(&As[cur ^ 1][srow * APAD + sk]) = cvt_bf8(a0, a1);
            *reinterpret_cast<u16x8*>(&Ws[cur ^ 1][srow * APAD + sk]) = wv;
        }
        __syncthreads();
        cur ^= 1;
    }

    // epilogue: C layout col=lane&15, row=(lane>>4)*4+i
    #pragma unroll
    for (int cb = 0; cb < 4; ++cb) {
        #pragma unroll
        for (int i = 0; i < 4; ++i) {
            int row = r0 + 16 * wave + (lane >> 4) * 4 + i;
            if (row < nrows)
                part[((size_t)kg * prow + row) * DEMB + 16 * cb + col16] = acc[cb][i];
        }
    }
}

// Reduce support partials + bias, L2-normalize -> sn [S][64]
__global__ void support_finalize(const float* __restrict__ spart,
                                 const float* __restrict__ bias,
                                 float* __restrict__ sn, int S, int nkg)
{
    int s = blockIdx.x;
    int c = threadIdx.x;  // 64
    float e = bias[c];
    for (int g = 0; g < nkg; ++g)
        e += spart[((size_t)g * 128 + s) * DEMB + c];
    float ss = e * e;
    #pragma unroll
    for (int o = 32; o >= 1; o >>= 1) ss += __shfl_xor(ss, o, 64);
    sn[(size_t)s * DEMB + c] = e / fmaxf(sqrtf(ss), 1e-8f);
}

// Fused: query reduce+bias+normalize, cosine sims, softmax, one-hot bins.
__global__ __launch_bounds__(256) void attend(
    const float* __restrict__ qpart, const float* __restrict__ sn_g,
    const float* __restrict__ bias, const int* __restrict__ labels,
    const int* __restrict__ p_nway, float* __restrict__ out,
    int S, int Q, int nkg)
{
    __shared__ float sn[100][65];
    __shared__ float qn[4][64];
    __shared__ float bins[4][32];
    __shared__ int   lab[100];

    const int tid  = threadIdx.x;
    const int w    = tid >> 6;
    const int lane = tid & 63;
    const int nw   = *p_nway;

    for (int i = tid; i < S * DEMB; i += 256) sn[i >> 6][i & 63] = sn_g[i];
    if (tid < S) lab[tid] = labels[tid];

    const int q = blockIdx.x * 4 + w;

    float e = bias[lane];
    for (int g = 0; g < nkg; ++g)
        e += qpart[((size_t)g * Q + q) * DEMB + lane];
    float ss = e * e;
    #pragma unroll
    for (int o = 32; o >= 1; o >>= 1) ss += __shfl_xor(ss, o, 64);
    e /= fmaxf(sqrtf(ss), 1e-8f);
    qn[w][lane] = e;
    if (lane < 32) bins[w][lane] = 0.f;
    __syncthreads();

    const bool v1 = (lane + 64) < S;
    const int  s1 = v1 ? lane + 64 : 0;
    float sim0 = 0.f, sim1 = 0.f;
    #pragma unroll 8
    for (int c = 0; c < DEMB; ++c) {
        float qc = qn[w][c];
        sim0 += qc * sn[lane][c];
        sim1 += qc * sn[s1][c];
    }
    if (!v1) sim1 = -INFINITY;

    float lm = fmaxf(sim0, sim1);
    #pragma unroll
    for (int o = 32; o >= 1; o >>= 1) lm = fmaxf(lm, __shfl_xor(lm, o, 64));
    float e0 = __expf(sim0 - lm);
    float e1 = v1 ? __expf(sim1 - lm) : 0.f;
    float d = e0 + e1;
    #pragma unroll
    for (int o = 32; o >= 1; o >>= 1) d += __shfl_xor(d, o, 64);

    atomicAdd(&bins[w][lab[lane]], e0);
    if (v1) atomicAdd(&bins[w][lab[s1]], e1);
    __syncthreads();

    if (lane < nw) out[(size_t)q * nw + lane] = bins[w][lane] / d;
}

extern "C" void kernel_launch(void* const* d_in, const int* in_sizes, int n_in,
                              void* d_out, int out_size, void* d_ws, size_t ws_size,
                              hipStream_t stream)
{
    const float* sup    = (const float*)d_in[0];
    const int*   labels = (const int*)d_in[1];
    const float* qry    = (const float*)d_in[2];
    const int*   p_nway = (const int*)d_in[3];
    const float* W      = (const float*)d_in[5];
    const float* bias   = (const float*)d_in[6];
    float* out = (float*)d_out;

    const int D   = DEMB;                 // 64
    const int Din = in_sizes[5] / D;      // 21168
    const int Q   = in_sizes[2] / Din;    // 4096
    const int S   = in_sizes[1];          // 100

    const int nchunk  = (Din + 31) / 32;  // 662
    const int Wstride = nchunk * 32;      // 21184

    // workspace layout
    char* wsb = (char*)d_ws;
    size_t wt_bytes = (size_t)64 * Wstride * sizeof(unsigned short); // 2.71 MB
    wt_bytes = (wt_bytes + 255) & ~(size_t)255;
    size_t sn_bytes = (size_t)S * D * sizeof(float);
    sn_bytes = (sn_bytes + 255) & ~(size_t)255;
    size_t per_ks = ((size_t)Q * D + 128 * D) * sizeof(float);

    size_t fixed = wt_bytes + sn_bytes;
    int ks = 1;
    if (ws_size > fixed + per_ks) {
        size_t avail = (ws_size - fixed) / per_ks;
        ks = (int)(avail < KSMAX ? avail : KSMAX);
        if (ks < 1) ks = 1;
    }
    const int cpk = (nchunk + ks - 1) / ks;       // chunks per K-group
    const int nkg = (nchunk + cpk - 1) / cpk;     // actual # groups

    unsigned short* Wt = (unsigned short*)wsb;
    float* sn    = (float*)(wsb + wt_bytes);
    float* spart = (float*)(wsb + wt_bytes + sn_bytes);
    float* qpart = spart + (size_t)nkg * 128 * D;

    hipLaunchKernelGGL(prep_wt, dim3((Din + 63) / 64), dim3(256), 0, stream,
                       W, Wt, Din, Wstride);

    const int nQb = (Q + BM - 1) / BM;          // 64
    const int nSb = (S + BM - 1) / BM;          // 2
    hipLaunchKernelGGL(gemm_mfma, dim3(nQb + nSb, nkg), dim3(256), 0, stream,
                       qry, sup, Wt, qpart, spart, Q, S, Din, Wstride, nQb, cpk, nchunk);

    hipLaunchKernelGGL(support_finalize, dim3(S), dim3(64), 0, stream,
                       spart, bias, sn, S, nkg);

    hipLaunchKernelGGL(attend, dim3(Q / 4), dim3(256), 0, stream,
                       qpart, sn, bias, labels, p_nway, out, S, Q, nkg);
}

// Round 10
// 119.794 us; speedup vs baseline: 1.3554x; 1.1224x over previous
//
#include <hip/hip_runtime.h>
#include <hip/hip_bf16.h>
#include <math.h>

#define DEMB 64
#define BM   64
#define BKF  64    // floats of K per batch (2 MFMA chunks)
#define KSMAX 32

using short8 = __attribute__((ext_vector_type(8))) short;
using u16x8  = __attribute__((ext_vector_type(8))) unsigned short;
using f32x4  = __attribute__((ext_vector_type(4))) float;

__device__ __forceinline__ u16x8 cvt_bf8(float4 a0, float4 a1) {
    union { u16x8 s; __hip_bfloat16 h[8]; } u;
    u.h[0] = __float2bfloat16(a0.x);
    u.h[1] = __float2bfloat16(a0.y);
    u.h[2] = __float2bfloat16(a0.z);
    u.h[3] = __float2bfloat16(a0.w);
    u.h[4] = __float2bfloat16(a1.x);
    u.h[5] = __float2bfloat16(a1.y);
    u.h[6] = __float2bfloat16(a1.z);
    u.h[7] = __float2bfloat16(a1.w);
    return u.s;
}

// async global->LDS, 16 B per lane.
// NOTE semantics (m104/m173): GLOBAL source address is PER-LANE (caller must
// include the lane offset); LDS dest = wave-uniform base + lane*16 (automatic).
__device__ __forceinline__ void gl16(const void* gsrc, void* lds) {
    __builtin_amdgcn_global_load_lds(
        (const __attribute__((address_space(1))) unsigned int*)gsrc,
        (__attribute__((address_space(3))) unsigned int*)lds,
        16, 0, 0);
}

// W [Din][64] fp32 -> Wtk k-octet-major bf16: Wtk[(oct*64 + c)*8 + (k&7)],
// K zero-padded to Koct*8.
__global__ __launch_bounds__(256) void prep_wt(
    const float* __restrict__ W, unsigned short* __restrict__ Wtk, int Din)
{
    const int t = blockIdx.x * 256 + threadIdx.x;   // t = oct*64 + c
    const int oct = t >> 6, c = t & 63;
    union { u16x8 v; __hip_bfloat16 h[8]; } u;
    #pragma unroll
    for (int j = 0; j < 8; ++j) {
        int k = oct * 8 + j;
        float x = (k < Din) ? W[(size_t)k * DEMB + c] : 0.f;
        u.h[j] = __float2bfloat16(x);
    }
    *reinterpret_cast<u16x8*>(&Wtk[(size_t)t * 8]) = u.v;
}

// MFMA GEMM. A: fp32 via global_load_lds (4-row x 256 B segments/instr),
// XOR-swizzled quads (source-permuted + same XOR on read -> conflict-free).
// B: bf16 via global_load_lds from k-octet-major Wtk (contiguous 1 KB/wave,
// per-lane source = octet base + lane*16B). cvt to bf16 at fragment read.
// One barrier per 64-k batch.
__global__ __launch_bounds__(256) void gemm_mfma(
    const float* __restrict__ Xq, const float* __restrict__ Xs,
    const unsigned short* __restrict__ Wtk,
    float* __restrict__ qpart, float* __restrict__ spart,
    int Q, int S, int Din, int nQb, int cpk, int nbatch)
{
    __shared__ float          As[2][BM * BKF];     // 2 x 16 KB
    __shared__ unsigned short Bs[2][8 * 64 * 8];   // 2 x 8 KB

    const int tid  = threadIdx.x;
    const int wave = tid >> 6;
    const int lane = tid & 63;
    const int kg   = blockIdx.y;

    const bool isS = (int)blockIdx.x >= nQb;
    const float* X = isS ? Xs : Xq;
    const int nrows = isS ? S : Q;
    const int r0 = (isS ? ((int)blockIdx.x - nQb) : (int)blockIdx.x) * BM;
    float* part = isS ? spart : qpart;
    const int prow = isS ? 128 : Q;

    // staging lane coords
    const int g  = lane >> 4;   // row within 4-row group
    const int qp = lane & 15;   // swizzled quad position

    // fragment coords
    const int col16 = lane & 15;
    const int frow  = 16 * wave + col16;     // frow & 15 == col16
    const int fk    = (lane >> 4) * 8;

    f32x4 acc[4] = { {0.f,0.f,0.f,0.f}, {0.f,0.f,0.f,0.f},
                     {0.f,0.f,0.f,0.f}, {0.f,0.f,0.f,0.f} };

    const int b0 = kg * cpk;
    int b1 = b0 + cpk; if (b1 > nbatch) b1 = nbatch;

#define STAGE(P, B) do {                                                       \
    const int kb_ = (B) * BKF;                                                 \
    _Pragma("unroll")                                                          \
    for (int i = 0; i < 4; ++i) {                                              \
        int rg_ = r0 + 16 * wave + 4 * i + g;                                  \
        if (rg_ >= nrows) rg_ = nrows - 1;                                     \
        const int q_ = qp ^ (4 * i + g);                                       \
        int kq_ = kb_ + 4 * q_;                                                \
        if (kq_ >= Din) kq_ = 0;                                               \
        gl16(X + (size_t)rg_ * Din + kq_,                                      \
             &As[P][(16 * wave + 4 * i) * BKF]);                               \
    }                                                                          \
    _Pragma("unroll")                                                          \
    for (int j = 0; j < 2; ++j) {                                              \
        gl16(Wtk + ((size_t)((B) * 8 + 2 * wave + j) * 64 + lane) * 8,         \
             &Bs[P][(2 * wave + j) * 512]);                                    \
    }                                                                          \
} while (0)

#define COMPUTE(P, CC) do {                                                    \
    const int qa_ = (CC) * 8 + (fk >> 2);                                      \
    const float* Ab_ = &As[P][frow * BKF];                                     \
    float4 fa_ = *reinterpret_cast<const float4*>(Ab_ + ((qa_    ) ^ col16) * 4); \
    float4 fb_ = *reinterpret_cast<const float4*>(Ab_ + ((qa_ + 1) ^ col16) * 4); \
    u16x8 afu_ = cvt_bf8(fa_, fb_);                                            \
    short8 af_ = (short8)afu_;                                                 \
    const int ob_ = ((CC) * 4 + (fk >> 3)) * 64;                               \
    short8 b0_ = *reinterpret_cast<const short8*>(&Bs[P][(ob_ +  0 + col16) * 8]); \
    short8 b1_ = *reinterpret_cast<const short8*>(&Bs[P][(ob_ + 16 + col16) * 8]); \
    short8 b2_ = *reinterpret_cast<const short8*>(&Bs[P][(ob_ + 32 + col16) * 8]); \
    short8 b3_ = *reinterpret_cast<const short8*>(&Bs[P][(ob_ + 48 + col16) * 8]); \
    acc[0] = __builtin_amdgcn_mfma_f32_16x16x32_bf16(af_, b0_, acc[0], 0, 0, 0);  \
    acc[1] = __builtin_amdgcn_mfma_f32_16x16x32_bf16(af_, b1_, acc[1], 0, 0, 0);  \
    acc[2] = __builtin_amdgcn_mfma_f32_16x16x32_bf16(af_, b2_, acc[2], 0, 0, 0);  \
    acc[3] = __builtin_amdgcn_mfma_f32_16x16x32_bf16(af_, b3_, acc[3], 0, 0, 0);  \
} while (0)

    STAGE(0, b0);
    __syncthreads();

    int cur = 0;
    for (int b = b0; b < b1; ++b) {
        if (b + 1 < b1) STAGE(cur ^ 1, b + 1);
        COMPUTE(cur, 0);
        COMPUTE(cur, 1);
        __syncthreads();
        cur ^= 1;
    }

#undef STAGE
#undef COMPUTE

    // epilogue: C layout col=lane&15, row=(lane>>4)*4+i
    #pragma unroll
    for (int cb = 0; cb < 4; ++cb) {
        #pragma unroll
        for (int i = 0; i < 4; ++i) {
            int row = r0 + 16 * wave + (lane >> 4) * 4 + i;
            if (row < nrows)
                part[((size_t)kg * prow + row) * DEMB + 16 * cb + col16] = acc[cb][i];
        }
    }
}

// Reduce support partials + bias, L2-normalize -> sn [S][64]
__global__ void support_finalize(const float* __restrict__ spart,
                                 const float* __restrict__ bias,
                                 float* __restrict__ sn, int S, int nkg)
{
    int s = blockIdx.x;
    int c = threadIdx.x;  // 64
    float e = bias[c];
    for (int g = 0; g < nkg; ++g)
        e += spart[((size_t)g * 128 + s) * DEMB + c];
    float ss = e * e;
    #pragma unroll
    for (int o = 32; o >= 1; o >>= 1) ss += __shfl_xor(ss, o, 64);
    sn[(size_t)s * DEMB + c] = e / fmaxf(sqrtf(ss), 1e-8f);
}

// Fused: query reduce+bias+normalize, cosine sims, softmax, one-hot bins.
__global__ __launch_bounds__(256) void attend(
    const float* __restrict__ qpart, const float* __restrict__ sn_g,
    const float* __restrict__ bias, const int* __restrict__ labels,
    const int* __restrict__ p_nway, float* __restrict__ out,
    int S, int Q, int nkg)
{
    __shared__ float sn[100][65];
    __shared__ float qn[4][64];
    __shared__ float bins[4][32];
    __shared__ int   lab[100];

    const int tid  = threadIdx.x;
    const int w    = tid >> 6;
    const int lane = tid & 63;
    const int nw   = *p_nway;

    for (int i = tid; i < S * DEMB; i += 256) sn[i >> 6][i & 63] = sn_g[i];
    if (tid < S) lab[tid] = labels[tid];

    const int q = blockIdx.x * 4 + w;

    float e = bias[lane];
    for (int g = 0; g < nkg; ++g)
        e += qpart[((size_t)g * Q + q) * DEMB + lane];
    float ss = e * e;
    #pragma unroll
    for (int o = 32; o >= 1; o >>= 1) ss += __shfl_xor(ss, o, 64);
    e /= fmaxf(sqrtf(ss), 1e-8f);
    qn[w][lane] = e;
    if (lane < 32) bins[w][lane] = 0.f;
    __syncthreads();

    const bool v1 = (lane + 64) < S;
    const int  s1 = v1 ? lane + 64 : 0;
    float sim0 = 0.f, sim1 = 0.f;
    #pragma unroll 8
    for (int c = 0; c < DEMB; ++c) {
        float qc = qn[w][c];
        sim0 += qc * sn[lane][c];
        sim1 += qc * sn[s1][c];
    }
    if (!v1) sim1 = -INFINITY;

    float lm = fmaxf(sim0, sim1);
    #pragma unroll
    for (int o = 32; o >= 1; o >>= 1) lm = fmaxf(lm, __shfl_xor(lm, o, 64));
    float e0 = __expf(sim0 - lm);
    float e1 = v1 ? __expf(sim1 - lm) : 0.f;
    float d = e0 + e1;
    #pragma unroll
    for (int o = 32; o >= 1; o >>= 1) d += __shfl_xor(d, o, 64);

    atomicAdd(&bins[w][lab[lane]], e0);
    if (v1) atomicAdd(&bins[w][lab[s1]], e1);
    __syncthreads();

    if (lane < nw) out[(size_t)q * nw + lane] = bins[w][lane] / d;
}

extern "C" void kernel_launch(void* const* d_in, const int* in_sizes, int n_in,
                              void* d_out, int out_size, void* d_ws, size_t ws_size,
                              hipStream_t stream)
{
    const float* sup    = (const float*)d_in[0];
    const int*   labels = (const int*)d_in[1];
    const float* qry    = (const float*)d_in[2];
    const int*   p_nway = (const int*)d_in[3];
    const float* W      = (const float*)d_in[5];
    const float* bias   = (const float*)d_in[6];
    float* out = (float*)d_out;

    const int D   = DEMB;                 // 64
    const int Din = in_sizes[5] / D;      // 21168
    const int Q   = in_sizes[2] / Din;    // 4096
    const int S   = in_sizes[1];          // 100

    const int nbatch = (Din + BKF - 1) / BKF;   // 331
    const int Koct   = nbatch * 8;              // 2648

    // workspace layout
    char* wsb = (char*)d_ws;
    size_t wt_bytes = (size_t)Koct * 64 * 16;   // 2.71 MB (Koct*64 octets * 16 B)
    wt_bytes = (wt_bytes + 255) & ~(size_t)255;
    size_t sn_bytes = (size_t)S * D * sizeof(float);
    sn_bytes = (sn_bytes + 255) & ~(size_t)255;
    size_t per_ks = ((size_t)Q * D + 128 * D) * sizeof(float);

    size_t fixed = wt_bytes + sn_bytes;
    int ks = 1;
    if (ws_size > fixed + per_ks) {
        size_t avail = (ws_size - fixed) / per_ks;
        ks = (int)(avail < KSMAX ? avail : KSMAX);
        if (ks < 1) ks = 1;
    }
    const int cpk = (nbatch + ks - 1) / ks;       // batches per K-group
    const int nkg = (nbatch + cpk - 1) / cpk;     // actual # groups

    unsigned short* Wtk = (unsigned short*)wsb;
    float* sn    = (float*)(wsb + wt_bytes);
    float* spart = (float*)(wsb + wt_bytes + sn_bytes);
    float* qpart = spart + (size_t)nkg * 128 * D;

    hipLaunchKernelGGL(prep_wt, dim3((Koct * 64) / 256), dim3(256), 0, stream,
                       W, Wtk, Din);

    const int nQb = (Q + BM - 1) / BM;          // 64
    const int nSb = (S + BM - 1) / BM;          // 2
    hipLaunchKernelGGL(gemm_mfma, dim3(nQb + nSb, nkg), dim3(256), 0, stream,
                       qry, sup, Wtk, qpart, spart, Q, S, Din, nQb, cpk, nbatch);

    hipLaunchKernelGGL(support_finalize, dim3(S), dim3(64), 0, stream,
                       spart, bias, sn, S, nkg);

    hipLaunchKernelGGL(attend, dim3(Q / 4), dim3(256), 0, stream,
                       qpart, sn, bias, labels, p_nway, out, S, Q, nkg);
}

// Round 11
// 117.736 us; speedup vs baseline: 1.3791x; 1.0175x over previous
//
#include <hip/hip_runtime.h>
#include <hip/hip_bf16.h>
#include <math.h>

#define DEMB 64
#define BM   64
#define BKF  64    // floats of K per batch (2 MFMA chunks)
#define KSMAX 16   // 66*16=1056 blocks; 72KB LDS -> 2 blocks/CU

using short8 = __attribute__((ext_vector_type(8))) short;
using u16x8  = __attribute__((ext_vector_type(8))) unsigned short;
using f32x4  = __attribute__((ext_vector_type(4))) float;

__device__ __forceinline__ u16x8 cvt_bf8(float4 a0, float4 a1) {
    union { u16x8 s; __hip_bfloat16 h[8]; } u;
    u.h[0] = __float2bfloat16(a0.x);
    u.h[1] = __float2bfloat16(a0.y);
    u.h[2] = __float2bfloat16(a0.z);
    u.h[3] = __float2bfloat16(a0.w);
    u.h[4] = __float2bfloat16(a1.x);
    u.h[5] = __float2bfloat16(a1.y);
    u.h[6] = __float2bfloat16(a1.z);
    u.h[7] = __float2bfloat16(a1.w);
    return u.s;
}

// async global->LDS, 16 B per lane. GLOBAL source is PER-LANE; LDS dest =
// wave-uniform base + lane*16 (automatic).
__device__ __forceinline__ void gl16(const void* gsrc, void* lds) {
    __builtin_amdgcn_global_load_lds(
        (const __attribute__((address_space(1))) unsigned int*)gsrc,
        (__attribute__((address_space(3))) unsigned int*)lds,
        16, 0, 0);
}

// W [Din][64] fp32 -> Wtk k-octet-major bf16: Wtk[(oct*64 + c)*8 + (k&7)],
// K zero-padded.
__global__ __launch_bounds__(256) void prep_wt(
    const float* __restrict__ W, unsigned short* __restrict__ Wtk, int Din)
{
    const int t = blockIdx.x * 256 + threadIdx.x;   // t = oct*64 + c
    const int oct = t >> 6, c = t & 63;
    union { u16x8 v; __hip_bfloat16 h[8]; } u;
    #pragma unroll
    for (int j = 0; j < 8; ++j) {
        int k = oct * 8 + j;
        float x = (k < Din) ? W[(size_t)k * DEMB + c] : 0.f;
        u.h[j] = __float2bfloat16(x);
    }
    *reinterpret_cast<u16x8*>(&Wtk[(size_t)t * 8]) = u.v;
}

// MFMA GEMM, 3-slot LDS ring + counted vmcnt (loads stay in flight across
// raw s_barrier). Per wave per batch: exactly 6 global_load_lds (4 A + 2 B).
__global__ __launch_bounds__(256) void gemm_mfma(
    const float* __restrict__ Xq, const float* __restrict__ Xs,
    const unsigned short* __restrict__ Wtk,
    float* __restrict__ qpart, float* __restrict__ spart,
    int Q, int S, int Din, int nQb, int cpk, int nbatch)
{
    __shared__ float          As[3][BM * BKF];     // 3 x 16 KB
    __shared__ unsigned short Bs[3][8 * 64 * 8];   // 3 x 8 KB

    const int tid  = threadIdx.x;
    const int wave = tid >> 6;
    const int lane = tid & 63;
    const int kg   = blockIdx.y;

    const bool isS = (int)blockIdx.x >= nQb;
    const float* X = isS ? Xs : Xq;
    const int nrows = isS ? S : Q;
    const int r0 = (isS ? ((int)blockIdx.x - nQb) : (int)blockIdx.x) * BM;
    float* part = isS ? spart : qpart;
    const int prow = isS ? 128 : Q;

    // staging lane coords
    const int g  = lane >> 4;   // row within 4-row group
    const int qp = lane & 15;   // swizzled quad position

    // fragment coords
    const int col16 = lane & 15;
    const int frow  = 16 * wave + col16;
    const int fk    = (lane >> 4) * 8;

    f32x4 acc[4] = { {0.f,0.f,0.f,0.f}, {0.f,0.f,0.f,0.f},
                     {0.f,0.f,0.f,0.f}, {0.f,0.f,0.f,0.f} };

    const int b0 = kg * cpk;
    int b1 = b0 + cpk; if (b1 > nbatch) b1 = nbatch;

#define STAGE(SL, B) do {                                                      \
    const int kb_ = (B) * BKF;                                                 \
    _Pragma("unroll")                                                          \
    for (int i = 0; i < 4; ++i) {                                              \
        int rg_ = r0 + 16 * wave + 4 * i + g;                                  \
        if (rg_ >= nrows) rg_ = nrows - 1;                                     \
        const int q_ = qp ^ (4 * i + g);                                       \
        int kq_ = kb_ + 4 * q_;                                                \
        if (kq_ >= Din) kq_ = 0;                                               \
        gl16(X + (size_t)rg_ * Din + kq_,                                      \
             &As[SL][(16 * wave + 4 * i) * BKF]);                              \
    }                                                                          \
    _Pragma("unroll")                                                          \
    for (int j = 0; j < 2; ++j) {                                              \
        gl16(Wtk + ((size_t)((B) * 8 + 2 * wave + j) * 64 + lane) * 8,         \
             &Bs[SL][(2 * wave + j) * 512]);                                   \
    }                                                                          \
} while (0)

#define COMPUTE(SL, CC) do {                                                   \
    const int qa_ = (CC) * 8 + (fk >> 2);                                      \
    const float* Ab_ = &As[SL][frow * BKF];                                    \
    float4 fa_ = *reinterpret_cast<const float4*>(Ab_ + ((qa_    ) ^ col16) * 4); \
    float4 fb_ = *reinterpret_cast<const float4*>(Ab_ + ((qa_ + 1) ^ col16) * 4); \
    u16x8 afu_ = cvt_bf8(fa_, fb_);                                            \
    short8 af_ = (short8)afu_;                                                 \
    const int ob_ = ((CC) * 4 + (fk >> 3)) * 64;                               \
    short8 b0_ = *reinterpret_cast<const short8*>(&Bs[SL][(ob_ +  0 + col16) * 8]); \
    short8 b1_ = *reinterpret_cast<const short8*>(&Bs[SL][(ob_ + 16 + col16) * 8]); \
    short8 b2_ = *reinterpret_cast<const short8*>(&Bs[SL][(ob_ + 32 + col16) * 8]); \
    short8 b3_ = *reinterpret_cast<const short8*>(&Bs[SL][(ob_ + 48 + col16) * 8]); \
    acc[0] = __builtin_amdgcn_mfma_f32_16x16x32_bf16(af_, b0_, acc[0], 0, 0, 0);  \
    acc[1] = __builtin_amdgcn_mfma_f32_16x16x32_bf16(af_, b1_, acc[1], 0, 0, 0);  \
    acc[2] = __builtin_amdgcn_mfma_f32_16x16x32_bf16(af_, b2_, acc[2], 0, 0, 0);  \
    acc[3] = __builtin_amdgcn_mfma_f32_16x16x32_bf16(af_, b3_, acc[3], 0, 0, 0);  \
} while (0)

    // prologue: issue batches b0 and b0+1; do NOT drain.
    STAGE(0, b0);
    if (b0 + 1 < b1) STAGE(1, b0 + 1);

    for (int b = b0; b < b1; ++b) {
        // own-wave loads for batch b complete (6 per batch, in-order retire):
        if (b + 1 < b1) asm volatile("s_waitcnt vmcnt(6)" ::: "memory");
        else            asm volatile("s_waitcnt vmcnt(0)" ::: "memory");
        __builtin_amdgcn_s_barrier();   // all waves' batch-b loads landed

        const int sl = (b - b0) % 3;
        if (b + 2 < b1) STAGE((sl + 2) % 3, b + 2);   // overwrite slot(b-1): safe post-barrier

        COMPUTE(sl, 0);
        COMPUTE(sl, 1);
    }

#undef STAGE
#undef COMPUTE

    // epilogue: C layout col=lane&15, row=(lane>>4)*4+i
    #pragma unroll
    for (int cb = 0; cb < 4; ++cb) {
        #pragma unroll
        for (int i = 0; i < 4; ++i) {
            int row = r0 + 16 * wave + (lane >> 4) * 4 + i;
            if (row < nrows)
                part[((size_t)kg * prow + row) * DEMB + 16 * cb + col16] = acc[cb][i];
        }
    }
}

// Reduce support partials + bias, L2-normalize -> sn [S][64]
__global__ void support_finalize(const float* __restrict__ spart,
                                 const float* __restrict__ bias,
                                 float* __restrict__ sn, int S, int nkg)
{
    int s = blockIdx.x;
    int c = threadIdx.x;  // 64
    float e = bias[c];
    for (int g = 0; g < nkg; ++g)
        e += spart[((size_t)g * 128 + s) * DEMB + c];
    float ss = e * e;
    #pragma unroll
    for (int o = 32; o >= 1; o >>= 1) ss += __shfl_xor(ss, o, 64);
    sn[(size_t)s * DEMB + c] = e / fmaxf(sqrtf(ss), 1e-8f);
}

// Fused: query reduce+bias+normalize, cosine sims, softmax, one-hot bins.
__global__ __launch_bounds__(256) void attend(
    const float* __restrict__ qpart, const float* __restrict__ sn_g,
    const float* __restrict__ bias, const int* __restrict__ labels,
    const int* __restrict__ p_nway, float* __restrict__ out,
    int S, int Q, int nkg)
{
    __shared__ float sn[100][65];
    __shared__ float qn[4][64];
    __shared__ float bins[4][32];
    __shared__ int   lab[100];

    const int tid  = threadIdx.x;
    const int w    = tid >> 6;
    const int lane = tid & 63;
    const int nw   = *p_nway;

    for (int i = tid; i < S * DEMB; i += 256) sn[i >> 6][i & 63] = sn_g[i];
    if (tid < S) lab[tid] = labels[tid];

    const int q = blockIdx.x * 4 + w;

    float e = bias[lane];
    for (int g = 0; g < nkg; ++g)
        e += qpart[((size_t)g * Q + q) * DEMB + lane];
    float ss = e * e;
    #pragma unroll
    for (int o = 32; o >= 1; o >>= 1) ss += __shfl_xor(ss, o, 64);
    e /= fmaxf(sqrtf(ss), 1e-8f);
    qn[w][lane] = e;
    if (lane < 32) bins[w][lane] = 0.f;
    __syncthreads();

    const bool v1 = (lane + 64) < S;
    const int  s1 = v1 ? lane + 64 : 0;
    float sim0 = 0.f, sim1 = 0.f;
    #pragma unroll 8
    for (int c = 0; c < DEMB; ++c) {
        float qc = qn[w][c];
        sim0 += qc * sn[lane][c];
        sim1 += qc * sn[s1][c];
    }
    if (!v1) sim1 = -INFINITY;

    float lm = fmaxf(sim0, sim1);
    #pragma unroll
    for (int o = 32; o >= 1; o >>= 1) lm = fmaxf(lm, __shfl_xor(lm, o, 64));
    float e0 = __expf(sim0 - lm);
    float e1 = v1 ? __expf(sim1 - lm) : 0.f;
    float d = e0 + e1;
    #pragma unroll
    for (int o = 32; o >= 1; o >>= 1) d += __shfl_xor(d, o, 64);

    atomicAdd(&bins[w][lab[lane]], e0);
    if (v1) atomicAdd(&bins[w][lab[s1]], e1);
    __syncthreads();

    if (lane < nw) out[(size_t)q * nw + lane] = bins[w][lane] / d;
}

extern "C" void kernel_launch(void* const* d_in, const int* in_sizes, int n_in,
                              void* d_out, int out_size, void* d_ws, size_t ws_size,
                              hipStream_t stream)
{
    const float* sup    = (const float*)d_in[0];
    const int*   labels = (const int*)d_in[1];
    const float* qry    = (const float*)d_in[2];
    const int*   p_nway = (const int*)d_in[3];
    const float* W      = (const float*)d_in[5];
    const float* bias   = (const float*)d_in[6];
    float* out = (float*)d_out;

    const int D   = DEMB;                 // 64
    const int Din = in_sizes[5] / D;      // 21168
    const int Q   = in_sizes[2] / Din;    // 4096
    const int S   = in_sizes[1];          // 100

    const int nbatch = (Din + BKF - 1) / BKF;   // 331
    const int Koct   = nbatch * 8;              // 2648

    // workspace layout
    char* wsb = (char*)d_ws;
    size_t wt_bytes = (size_t)Koct * 64 * 16;   // 2.71 MB
    wt_bytes = (wt_bytes + 255) & ~(size_t)255;
    size_t sn_bytes = (size_t)S * D * sizeof(float);
    sn_bytes = (sn_bytes + 255) & ~(size_t)255;
    size_t per_ks = ((size_t)Q * D + 128 * D) * sizeof(float);

    size_t fixed = wt_bytes + sn_bytes;
    int ks = 1;
    if (ws_size > fixed + per_ks) {
        size_t avail = (ws_size - fixed) / per_ks;
        ks = (int)(avail < KSMAX ? avail : KSMAX);
        if (ks < 1) ks = 1;
    }
    const int cpk = (nbatch + ks - 1) / ks;       // batches per K-group
    const int nkg = (nbatch + cpk - 1) / cpk;     // actual # groups

    unsigned short* Wtk = (unsigned short*)wsb;
    float* sn    = (float*)(wsb + wt_bytes);
    float* spart = (float*)(wsb + wt_bytes + sn_bytes);
    float* qpart = spart + (size_t)nkg * 128 * D;

    hipLaunchKernelGGL(prep_wt, dim3((Koct * 64) / 256), dim3(256), 0, stream,
                       W, Wtk, Din);

    const int nQb = (Q + BM - 1) / BM;          // 64
    const int nSb = (S + BM - 1) / BM;          // 2
    hipLaunchKernelGGL(gemm_mfma, dim3(nQb + nSb, nkg), dim3(256), 0, stream,
                       qry, sup, Wtk, qpart, spart, Q, S, Din, nQb, cpk, nbatch);

    hipLaunchKernelGGL(support_finalize, dim3(S), dim3(64), 0, stream,
                       spart, bias, sn, S, nkg);

    hipLaunchKernelGGL(attend, dim3(Q / 4), dim3(256), 0, stream,
                       qpart, sn, bias, labels, p_nway, out, S, Q, nkg);
}